// Round 7
// baseline (249.936 us; speedup 1.0000x reference)
//
#include <hip/hip_runtime.h>
#include <hip/hip_bf16.h>
#include <stdint.h>

#define N_NODES 4096
#define HIDDEN 256
#define NHEAD 4
#define DHEAD 64
#define NEDGE 131072
#define MASK_WORDS 128   // 4096 bits / 32
#define KIN 64           // combined-proj K padded 45 -> 64
#define CAP 512          // per-row neighbor cap; degree ~Poisson(33), P(>512)=0

typedef __attribute__((ext_vector_type(8))) short bf16x8;
typedef __attribute__((ext_vector_type(4))) float f32x4;
typedef __hip_bfloat16 bf16;

__device__ __forceinline__ float b2f(unsigned short s) {
    union { float f; unsigned u; } x;
    x.u = ((unsigned)s) << 16;
    return x.f;
}
__device__ __forceinline__ unsigned short f2bu(float f) {
    bf16 b = __float2bfloat16(f);
    return *(unsigned short*)&b;
}

// ---------------------------------------------------------------------------
// Dispatch 1: prep — mask zero (uint4), nf pad+cvt, combined W'/b', WoT.
// W'/b' dots are split 4-ways (64 iters/thread + shfl_down reduce) to cut the
// serial-FMA critical path; lanes 4t..4t+3 of a dot are adjacent so the
// reduction stays inside a wave.
// Zero->scatter ordering across the dispatch boundary (scatter in dispatch 2).
// ---------------------------------------------------------------------------
__global__ __launch_bounds__(256) void prep_kernel(
    const float* __restrict__ nf,
    const float* __restrict__ W_in, const float* __restrict__ b_in,
    const float* __restrict__ Wq, const float* __restrict__ bq,
    const float* __restrict__ Wk, const float* __restrict__ bk,
    const float* __restrict__ Wv, const float* __restrict__ bv,
    const float* __restrict__ Wo,
    unsigned int* __restrict__ mask, bf16* __restrict__ nfp,
    bf16* __restrict__ WqkvT, float* __restrict__ bqkv,
    bf16* __restrict__ WoT)
{
    int t = blockIdx.x * 256 + threadIdx.x;
    if (t < 131072) {                           // 2 MiB mask zero, 16B/thread
        ((uint4*)mask)[t] = make_uint4(0, 0, 0, 0);
        return;
    }
    t -= 131072;
    if (t < N_NODES * KIN) {                    // nfp[row][c]
        int row = t >> 6, c = t & 63;
        float v = (c < 45) ? nf[row * 45 + c] : 0.f;
        nfp[t] = __float2bfloat16(v);
        return;
    }
    t -= N_NODES * KIN;
    if (t < 4 * 3 * 256 * KIN) {                // W'T[which][n][kk], 4 threads/dot
        int part = t & 3;                       // which quarter of the 256-sum
        int d = t >> 2;                         // dot id
        int which = d >> 14, r = d & 16383;
        int n = r & 255, kk = r >> 8;           // consecutive d -> consecutive n
        const float* W = (which == 0) ? Wq : (which == 1) ? Wk : Wv;
        float dot = 0.f;
        if (kk < 45) {
            const float* wrow = W_in + kk * 256 + part * 64;
            const float* wcol = W + (size_t)(part * 64) * 256 + n;
            for (int c = 0; c < 64; ++c)
                dot += wrow[c] * wcol[(size_t)c * 256];
        }
        // lanes 4t..4t+3 hold quarters of the same dot (part = lane&3)
        dot += __shfl_down(dot, 1, 64);
        dot += __shfl_down(dot, 2, 64);
        if (part == 0)
            WqkvT[(size_t)which * 16384 + (size_t)n * KIN + kk] = __float2bfloat16(dot);
        return;
    }
    t -= 4 * 3 * 256 * KIN;
    if (t < 4 * 3 * 256) {                      // b'[which][n], 4 threads/dot
        int part = t & 3;
        int d = t >> 2;
        int which = d >> 8, n = d & 255;
        const float* W = (which == 0) ? Wq : (which == 1) ? Wk : Wv;
        const float* b = (which == 0) ? bq : (which == 1) ? bk : bv;
        float acc = 0.f;
        const float* bi = b_in + part * 64;
        const float* wcol = W + (size_t)(part * 64) * 256 + n;
        for (int c = 0; c < 64; ++c)
            acc += bi[c] * wcol[(size_t)c * 256];
        acc += __shfl_down(acc, 1, 64);
        acc += __shfl_down(acc, 2, 64);
        if (part == 0) bqkv[d] = acc + b[n];
        return;
    }
    t -= 4 * 3 * 256;
    if (t < 65536) {                            // WoT[n][kk] = Wo[kk][n]
        int kk = t >> 8, n = t & 255;           // coalesced read of Wo
        WoT[(size_t)n * 256 + kk] = __float2bfloat16(Wo[(size_t)kk * 256 + n]);
    }
}

// ---------------------------------------------------------------------------
// bf16 MFMA GEMM body: C(M x 256) = A(M x K) @ Bt^T + bias.
// Frag layout (m89-verified): A[m=lane&15][k=quad*8+j]; D col=lane&15,
// row=quad*4+reg.
// ---------------------------------------------------------------------------
template <bool OUT_BF16>
__device__ __forceinline__ void gemm_body(
    const bf16* __restrict__ A, const bf16* __restrict__ Bt,
    const float* __restrict__ bias, void* __restrict__ Cv,
    int K, int m_base, int n0)
{
    const int lane = threadIdx.x & 63;
    const int row = lane & 15, quad = lane >> 4;
    f32x4 acc0 = {0.f, 0.f, 0.f, 0.f};
    f32x4 acc1 = {0.f, 0.f, 0.f, 0.f};
    const short* Ap = (const short*)A;
    const short* Bp = (const short*)Bt;

    for (int k0 = 0; k0 < K; k0 += 32) {
        bf16x8 b  = *(const bf16x8*)(Bp + (size_t)(n0 + row) * K + k0 + quad * 8);
        bf16x8 a0 = *(const bf16x8*)(Ap + (size_t)(m_base + row) * K + k0 + quad * 8);
        bf16x8 a1 = *(const bf16x8*)(Ap + (size_t)(m_base + 16 + row) * K + k0 + quad * 8);
        acc0 = __builtin_amdgcn_mfma_f32_16x16x32_bf16(a0, b, acc0, 0, 0, 0);
        acc1 = __builtin_amdgcn_mfma_f32_16x16x32_bf16(a1, b, acc1, 0, 0, 0);
    }

    const int col = row;
    const float bval = bias[n0 + col];
#pragma unroll
    for (int e = 0; e < 4; ++e) {
        int m0 = m_base + quad * 4 + e;
        int m1 = m0 + 16;
        float v0 = acc0[e] + bval;
        float v1 = acc1[e] + bval;
        if (OUT_BF16) {
            ((bf16*)Cv)[(size_t)m0 * HIDDEN + n0 + col] = __float2bfloat16(v0);
            ((bf16*)Cv)[(size_t)m1 * HIDDEN + n0 + col] = __float2bfloat16(v1);
        } else {
            ((float*)Cv)[(size_t)m0 * HIDDEN + n0 + col] = v0;
            ((float*)Cv)[(size_t)m1 * HIDDEN + n0 + col] = v1;
        }
    }
}

// ---------------------------------------------------------------------------
// Dispatch 2: QKV MFMA GEMM (q,k,v all bf16) + edge/diag bitmask scatter.
// Bitmask dedupes duplicate edges (must not double-count in softmax).
// ---------------------------------------------------------------------------
__global__ __launch_bounds__(256) void qkv_scatter_kernel(
    const bf16* __restrict__ nfp, const bf16* __restrict__ WqkvT,
    const float* __restrict__ bqkv, const int* __restrict__ eidx,
    bf16* __restrict__ q, bf16* __restrict__ k, bf16* __restrict__ v,
    unsigned int* __restrict__ mask)
{
    int bx = blockIdx.x;
    if (bx < 1536) {
        int ntile = bx >> 5, mrow = bx & 31;
        int which = ntile >> 4;
        const bf16* Bt = WqkvT + (size_t)which * 16384;
        const float* bias = bqkv + which * 256;
        int wave = threadIdx.x >> 6;
        int mb = mrow * 128 + wave * 32;
        int n0 = (ntile & 15) * 16;
        bf16* C = (which == 0) ? q : (which == 1) ? k : v;
        gemm_body<true>(nfp, Bt, bias, C, KIN, mb, n0);
        return;
    }
    int t = (bx - 1536) * 256 + threadIdx.x;
    if (t < NEDGE) {
        int u = eidx[t], w = eidx[NEDGE + t];
        atomicOr(&mask[u * MASK_WORDS + (w >> 5)], 1u << (w & 31));
    } else {
        int i = t - NEDGE;
        if (i < N_NODES)
            atomicOr(&mask[i * MASK_WORDS + (i >> 5)], 1u << (i & 31));
    }
}

// ---------------------------------------------------------------------------
// Dispatch 3: sparse masked attention — wave-autonomous (wave = row, all 4
// heads). No __syncthreads. jlist via shfl prefix-scan. No max-shift:
// |s| <= ~30 so exp(s) is fp32-safe; softmax shift-invariant.
// Phase A: lane = neighbor, scores all 4 heads (k row read once, dt once).
// Phase B: lane = 4-dim group (d = 4*lane), full 256-dim v row per iteration.
// ---------------------------------------------------------------------------
__global__ __launch_bounds__(256) void attn_kernel(
    const bf16* __restrict__ q, const bf16* __restrict__ k,
    const bf16* __restrict__ v, const float* __restrict__ temporal,
    const unsigned int* __restrict__ mask, bf16* __restrict__ att)
{
    __shared__ int   jl[4][CAP];       // 8 KB
    __shared__ float qsw[4][HIDDEN];   // 4 KB
    __shared__ float pch[4][4][68];    // 4.25 KB (stride 68: no 4-way h conflict)
    const int w    = threadIdx.x >> 6;
    const int lane = threadIdx.x & 63;
    const int i    = blockIdx.x * 4 + w;

    // --- stage q row (bf16 -> fp32 LDS), wave-private ---
    {
        const unsigned short* qp = (const unsigned short*)q + (size_t)i * HIDDEN + 4 * lane;
        ushort4 q4 = *(const ushort4*)qp;
        qsw[w][4 * lane + 0] = b2f(q4.x);
        qsw[w][4 * lane + 1] = b2f(q4.y);
        qsw[w][4 * lane + 2] = b2f(q4.z);
        qsw[w][4 * lane + 3] = b2f(q4.w);
    }

    // --- build jlist: lane scans mask words 2*lane, 2*lane+1; shfl scan ---
    const unsigned int* mrow = mask + (size_t)i * MASK_WORDS;
    unsigned int w0 = mrow[2 * lane], w1 = mrow[2 * lane + 1];
    int c = __popc(w0) + __popc(w1);
    int inc = c;
#pragma unroll
    for (int off = 1; off < 64; off <<= 1) {
        int tt = __shfl_up(inc, off, 64);
        if (lane >= off) inc += tt;
    }
    const int nn0 = __shfl(inc, 63, 64);
    const int nn = (nn0 < CAP) ? nn0 : CAP;
    int pos = inc - c;
    if (pos + c <= CAP) {            // whole-lane guard (cheaper than per-bit)
        int jb = lane * 64;
        while (w0) {
            int b = __ffs(w0) - 1; w0 &= w0 - 1;
            jl[w][pos++] = jb + b;
        }
        jb += 32;
        while (w1) {
            int b = __ffs(w1) - 1; w1 &= w1 - 1;
            jl[w][pos++] = jb + b;
        }
    }
    // (wave-private LDS: compiler's lgkmcnt ordering suffices, no barrier)

    const float* trow = temporal + (size_t)i * N_NODES * 2;
    const unsigned short* kp = (const unsigned short*)k;
    const unsigned short* vp = (const unsigned short*)v;
    const int hsel = lane >> 4;

    float l0 = 0.f, l1 = 0.f, l2 = 0.f, l3 = 0.f;
    float a0 = 0.f, a1 = 0.f, a2 = 0.f, a3 = 0.f;

    for (int c0 = 0; c0 < nn; c0 += 64) {
        const int cend = min(64, nn - c0);
        // ---- Phase A: lane scores neighbor jl[w][c0+lane] for all 4 heads --
        int j = (lane < cend) ? jl[w][c0 + lane] : -1;
        float tb = 0.f;
        if (j >= 0) {
            float dt = trow[(size_t)j * 2];
            tb += 0.2f * (float)((dt >= 0.f)  & (dt <= 5.f));
            tb += 0.1f * (float)((dt >= 5.f)  & (dt <= 15.f));
            tb -= 0.1f * (float)((dt >= 60.f) & (dt <= 240.f));
        }
#pragma unroll
        for (int h = 0; h < 4; ++h) {
            float dot = 0.f;
            if (j >= 0) {
                const unsigned short* krow = kp + (size_t)j * HIDDEN + h * DHEAD;
#pragma unroll
                for (int t = 0; t < 8; ++t) {
                    bf16x8 k8 = *(const bf16x8*)(krow + t * 8);
                    f32x4 qa = *(const f32x4*)(&qsw[w][h * DHEAD + t * 8]);
                    f32x4 qb = *(const f32x4*)(&qsw[w][h * DHEAD + t * 8 + 4]);
                    dot += b2f((unsigned short)k8[0]) * qa[0];
                    dot += b2f((unsigned short)k8[1]) * qa[1];
                    dot += b2f((unsigned short)k8[2]) * qa[2];
                    dot += b2f((unsigned short)k8[3]) * qa[3];
                    dot += b2f((unsigned short)k8[4]) * qb[0];
                    dot += b2f((unsigned short)k8[5]) * qb[1];
                    dot += b2f((unsigned short)k8[6]) * qb[2];
                    dot += b2f((unsigned short)k8[7]) * qb[3];
                }
            }
            float s = (j >= 0) ? dot * 0.125f + tb : -3.0e38f;
            float p = __expf(s);                // invalid lanes -> 0
            float cs = p;
#pragma unroll
            for (int off = 32; off >= 1; off >>= 1)
                cs += __shfl_xor(cs, off, 64);
            pch[w][h][lane] = p;
            if (h == 0) l0 += cs; else if (h == 1) l1 += cs;
            else if (h == 2) l2 += cs; else l3 += cs;
        }
        // ---- Phase B: lane accumulates dims [4*lane, 4*lane+4) ----
        const float* ph = pch[w][hsel];
        int jj = 0;
        for (; jj + 4 <= cend; jj += 4) {
            int ja = jl[w][c0 + jj],     jb2 = jl[w][c0 + jj + 1];
            int jc = jl[w][c0 + jj + 2], jd  = jl[w][c0 + jj + 3];
            float pa = ph[jj], pb = ph[jj + 1], pc = ph[jj + 2], pd = ph[jj + 3];
            ushort4 va = *(const ushort4*)(vp + (size_t)ja  * HIDDEN + 4 * lane);
            ushort4 vb = *(const ushort4*)(vp + (size_t)jb2 * HIDDEN + 4 * lane);
            ushort4 vc = *(const ushort4*)(vp + (size_t)jc  * HIDDEN + 4 * lane);
            ushort4 vd = *(const ushort4*)(vp + (size_t)jd  * HIDDEN + 4 * lane);
            a0 += pa * b2f(va.x) + pb * b2f(vb.x) + pc * b2f(vc.x) + pd * b2f(vd.x);
            a1 += pa * b2f(va.y) + pb * b2f(vb.y) + pc * b2f(vc.y) + pd * b2f(vd.y);
            a2 += pa * b2f(va.z) + pb * b2f(vb.z) + pc * b2f(vc.z) + pd * b2f(vd.z);
            a3 += pa * b2f(va.w) + pb * b2f(vb.w) + pc * b2f(vc.w) + pd * b2f(vd.w);
        }
        for (; jj < cend; ++jj) {
            int jx = jl[w][c0 + jj];
            float px = ph[jj];
            ushort4 vx = *(const ushort4*)(vp + (size_t)jx * HIDDEN + 4 * lane);
            a0 += px * b2f(vx.x);
            a1 += px * b2f(vx.y);
            a2 += px * b2f(vx.z);
            a3 += px * b2f(vx.w);
        }
    }

    float lsel = (hsel == 0) ? l0 : (hsel == 1) ? l1 : (hsel == 2) ? l2 : l3;
    float inv = 1.f / lsel;
    ushort4 o;
    o.x = f2bu(a0 * inv);
    o.y = f2bu(a1 * inv);
    o.z = f2bu(a2 * inv);
    o.w = f2bu(a3 * inv);
    *(ushort4*)((unsigned short*)att + (size_t)i * HIDDEN + 4 * lane) = o;
}

// Dispatch 4: out = att @ Wo + bo, fp32 output
__global__ __launch_bounds__(256) void gemm_out_kernel(
    const bf16* __restrict__ att, const bf16* __restrict__ WoT,
    const float* __restrict__ bo, float* __restrict__ out)
{
    int wave = threadIdx.x >> 6;
    gemm_body<false>(att, WoT, bo, out, HIDDEN,
                     blockIdx.y * 128 + wave * 32, blockIdx.x * 16);
}

// ---------------------------------------------------------------------------
extern "C" void kernel_launch(void* const* d_in, const int* in_sizes, int n_in,
                              void* d_out, int out_size, void* d_ws, size_t ws_size,
                              hipStream_t stream) {
    const float* nf       = (const float*)d_in[0];
    const float* temporal = (const float*)d_in[1];
    const int*   eidx     = (const int*)  d_in[2];
    const float* W_in     = (const float*)d_in[3];
    const float* b_in     = (const float*)d_in[4];
    const float* Wq       = (const float*)d_in[5];
    const float* bq       = (const float*)d_in[6];
    const float* Wk       = (const float*)d_in[7];
    const float* bk       = (const float*)d_in[8];
    const float* Wv       = (const float*)d_in[9];
    const float* bv       = (const float*)d_in[10];
    const float* Wo       = (const float*)d_in[11];
    const float* bo       = (const float*)d_in[12];
    float* out = (float*)d_out;

    char* ws = (char*)d_ws;
    const size_t MiB = 1 << 20, KiB = 1 << 10;
    unsigned int* mask = (unsigned int*)(ws);                  // 2 MiB
    bf16*  nfp   = (bf16*)(ws + 2 * MiB);                      // 512 KiB
    bf16*  WqkvT = (bf16*)(ws + 2 * MiB + 512 * KiB);          // 96 KiB
    float* bqkv  = (float*)(ws + 2 * MiB + 640 * KiB);         // 3 KiB
    bf16*  WoT   = (bf16*)(ws + 3 * MiB);                      // 128 KiB
    bf16*  qb    = (bf16*)(ws + 4 * MiB);                      // 2 MiB
    bf16*  kb    = (bf16*)(ws + 6 * MiB);                      // 2 MiB
    bf16*  vb    = (bf16*)(ws + 8 * MiB);                      // 2 MiB
    bf16*  att   = (bf16*)(ws + 10 * MiB);                     // 2 MiB -> 12 MiB

    // 1. prep: mask zero + nf cvt + combined W'/b' (4-way split dots) + WoT
    {
        int total = 131072 + N_NODES * KIN + 4 * 3 * 256 * KIN + 4 * 3 * 256 + 65536;
        prep_kernel<<<(total + 255) / 256, 256, 0, stream>>>(
            nf, W_in, b_in, Wq, bq, Wk, bk, Wv, bv, Wo,
            mask, nfp, WqkvT, bqkv, WoT);
    }

    // 2. q,k,v = nf @ W' + b' (MFMA, K=64, all bf16) + edge/diag scatter
    qkv_scatter_kernel<<<1536 + 528, 256, 0, stream>>>(
        nfp, WqkvT, bqkv, eidx, qb, kb, vb, mask);

    // 3. sparse masked attention (wave = row, barrier-free)
    attn_kernel<<<N_NODES / 4, 256, 0, stream>>>(qb, kb, vb, temporal, mask, att);

    // 4. out = att @ Wo + bo (MFMA)
    gemm_out_kernel<<<dim3(16, 32), 256, 0, stream>>>(att, WoT, bo, out);
}

// Round 8
// 243.825 us; speedup vs baseline: 1.0251x; 1.0251x over previous
//
#include <hip/hip_runtime.h>
#include <hip/hip_bf16.h>
#include <stdint.h>

#define N_NODES 4096
#define HIDDEN 256
#define NHEAD 4
#define DHEAD 64
#define NEDGE 131072
#define MASK_WORDS 128   // 4096 bits / 32
#define KIN 64           // combined-proj K padded 45 -> 64
#define CAP 512          // per-row neighbor cap; degree ~Poisson(33), P(>512)=0

typedef __attribute__((ext_vector_type(8))) short bf16x8;
typedef __attribute__((ext_vector_type(4))) float f32x4;
typedef __hip_bfloat16 bf16;

__device__ __forceinline__ float b2f(unsigned short s) {
    union { float f; unsigned u; } x;
    x.u = ((unsigned)s) << 16;
    return x.f;
}
__device__ __forceinline__ unsigned short f2bu(float f) {
    bf16 b = __float2bfloat16(f);
    return *(unsigned short*)&b;
}

// ---------------------------------------------------------------------------
// Dispatch 1: prep — mask zero (uint4), nf pad+cvt, combined W'/b', WoT.
// NOTE (R7 post-mortem): keep the W'/b' dots as single-thread 256-iter chains.
// The 4-way split + shfl_down variant REGRESSED 244->250 µs: 4x more waves
// walking the same 1KiB-strided W columns, and the chain latency was already
// hidden by the concurrent mask-zero range in this dispatch.
// Zero->scatter ordering across the dispatch boundary (scatter in dispatch 2).
// ---------------------------------------------------------------------------
__global__ __launch_bounds__(256) void prep_kernel(
    const float* __restrict__ nf,
    const float* __restrict__ W_in, const float* __restrict__ b_in,
    const float* __restrict__ Wq, const float* __restrict__ bq,
    const float* __restrict__ Wk, const float* __restrict__ bk,
    const float* __restrict__ Wv, const float* __restrict__ bv,
    const float* __restrict__ Wo,
    unsigned int* __restrict__ mask, bf16* __restrict__ nfp,
    bf16* __restrict__ WqkvT, float* __restrict__ bqkv,
    bf16* __restrict__ WoT)
{
    int t = blockIdx.x * 256 + threadIdx.x;
    if (t < 131072) {                           // 2 MiB mask zero, 16B/thread
        ((uint4*)mask)[t] = make_uint4(0, 0, 0, 0);
        return;
    }
    t -= 131072;
    if (t < N_NODES * KIN) {                    // nfp[row][c]
        int row = t >> 6, c = t & 63;
        float v = (c < 45) ? nf[row * 45 + c] : 0.f;
        nfp[t] = __float2bfloat16(v);
        return;
    }
    t -= N_NODES * KIN;
    if (t < 3 * 256 * KIN) {                    // W'T[which][n][kk] = (W_in@W)[kk][n]
        int which = t >> 14, r = t & 16383;
        int n = r & 255, kk = r >> 8;           // consecutive t -> consecutive n
        const float* W = (which == 0) ? Wq : (which == 1) ? Wk : Wv;
        float dot = 0.f;
        if (kk < 45) {
            const float* wrow = W_in + kk * 256;   // wave-uniform reads
            for (int c = 0; c < 256; ++c)
                dot += wrow[c] * W[c * 256 + n];   // coalesced in n
        }
        WqkvT[(size_t)which * 16384 + (size_t)n * KIN + kk] = __float2bfloat16(dot);
        return;
    }
    t -= 3 * 256 * KIN;
    if (t < 3 * 256) {                          // b'[which][n] = b_in@W + b
        int which = t >> 8, n = t & 255;
        const float* W = (which == 0) ? Wq : (which == 1) ? Wk : Wv;
        const float* b = (which == 0) ? bq : (which == 1) ? bk : bv;
        float acc = b[n];
        for (int c = 0; c < 256; ++c)
            acc += b_in[c] * W[c * 256 + n];
        bqkv[t] = acc;
        return;
    }
    t -= 3 * 256;
    if (t < 65536) {                            // WoT[n][kk] = Wo[kk][n]
        int kk = t >> 8, n = t & 255;           // coalesced read of Wo
        WoT[(size_t)n * 256 + kk] = __float2bfloat16(Wo[(size_t)kk * 256 + n]);
    }
}

// ---------------------------------------------------------------------------
// bf16 MFMA GEMM body: C(M x 256) = A(M x K) @ Bt^T + bias.
// Frag layout (m89-verified): A[m=lane&15][k=quad*8+j]; D col=lane&15,
// row=quad*4+reg.
// ---------------------------------------------------------------------------
template <bool OUT_BF16>
__device__ __forceinline__ void gemm_body(
    const bf16* __restrict__ A, const bf16* __restrict__ Bt,
    const float* __restrict__ bias, void* __restrict__ Cv,
    int K, int m_base, int n0)
{
    const int lane = threadIdx.x & 63;
    const int row = lane & 15, quad = lane >> 4;
    f32x4 acc0 = {0.f, 0.f, 0.f, 0.f};
    f32x4 acc1 = {0.f, 0.f, 0.f, 0.f};
    const short* Ap = (const short*)A;
    const short* Bp = (const short*)Bt;

    for (int k0 = 0; k0 < K; k0 += 32) {
        bf16x8 b  = *(const bf16x8*)(Bp + (size_t)(n0 + row) * K + k0 + quad * 8);
        bf16x8 a0 = *(const bf16x8*)(Ap + (size_t)(m_base + row) * K + k0 + quad * 8);
        bf16x8 a1 = *(const bf16x8*)(Ap + (size_t)(m_base + 16 + row) * K + k0 + quad * 8);
        acc0 = __builtin_amdgcn_mfma_f32_16x16x32_bf16(a0, b, acc0, 0, 0, 0);
        acc1 = __builtin_amdgcn_mfma_f32_16x16x32_bf16(a1, b, acc1, 0, 0, 0);
    }

    const int col = row;
    const float bval = bias[n0 + col];
#pragma unroll
    for (int e = 0; e < 4; ++e) {
        int m0 = m_base + quad * 4 + e;
        int m1 = m0 + 16;
        float v0 = acc0[e] + bval;
        float v1 = acc1[e] + bval;
        if (OUT_BF16) {
            ((bf16*)Cv)[(size_t)m0 * HIDDEN + n0 + col] = __float2bfloat16(v0);
            ((bf16*)Cv)[(size_t)m1 * HIDDEN + n0 + col] = __float2bfloat16(v1);
        } else {
            ((float*)Cv)[(size_t)m0 * HIDDEN + n0 + col] = v0;
            ((float*)Cv)[(size_t)m1 * HIDDEN + n0 + col] = v1;
        }
    }
}

// ---------------------------------------------------------------------------
// Dispatch 2: QKV MFMA GEMM (q,k,v all bf16) + edge/diag bitmask scatter.
// Bitmask dedupes duplicate edges (must not double-count in softmax).
// ---------------------------------------------------------------------------
__global__ __launch_bounds__(256) void qkv_scatter_kernel(
    const bf16* __restrict__ nfp, const bf16* __restrict__ WqkvT,
    const float* __restrict__ bqkv, const int* __restrict__ eidx,
    bf16* __restrict__ q, bf16* __restrict__ k, bf16* __restrict__ v,
    unsigned int* __restrict__ mask)
{
    int bx = blockIdx.x;
    if (bx < 1536) {
        int ntile = bx >> 5, mrow = bx & 31;
        int which = ntile >> 4;
        const bf16* Bt = WqkvT + (size_t)which * 16384;
        const float* bias = bqkv + which * 256;
        int wave = threadIdx.x >> 6;
        int mb = mrow * 128 + wave * 32;
        int n0 = (ntile & 15) * 16;
        bf16* C = (which == 0) ? q : (which == 1) ? k : v;
        gemm_body<true>(nfp, Bt, bias, C, KIN, mb, n0);
        return;
    }
    int t = (bx - 1536) * 256 + threadIdx.x;
    if (t < NEDGE) {
        int u = eidx[t], w = eidx[NEDGE + t];
        atomicOr(&mask[u * MASK_WORDS + (w >> 5)], 1u << (w & 31));
    } else {
        int i = t - NEDGE;
        if (i < N_NODES)
            atomicOr(&mask[i * MASK_WORDS + (i >> 5)], 1u << (i & 31));
    }
}

// ---------------------------------------------------------------------------
// Dispatch 3: sparse masked attention — wave-autonomous (wave = row, all 4
// heads). No __syncthreads. jlist via shfl prefix-scan. No max-shift:
// |s| <= ~30 so exp(s) is fp32-safe; softmax shift-invariant.
// Phase A: lane = neighbor, scores all 4 heads (k row read once, dt once).
// Phase B: lane = 4-dim group (d = 4*lane), full 256-dim v row per iteration.
// ---------------------------------------------------------------------------
__global__ __launch_bounds__(256) void attn_kernel(
    const bf16* __restrict__ q, const bf16* __restrict__ k,
    const bf16* __restrict__ v, const float* __restrict__ temporal,
    const unsigned int* __restrict__ mask, bf16* __restrict__ att)
{
    __shared__ int   jl[4][CAP];       // 8 KB
    __shared__ float qsw[4][HIDDEN];   // 4 KB
    __shared__ float pch[4][4][68];    // 4.25 KB (stride 68: no 4-way h conflict)
    const int w    = threadIdx.x >> 6;
    const int lane = threadIdx.x & 63;
    const int i    = blockIdx.x * 4 + w;

    // --- stage q row (bf16 -> fp32 LDS), wave-private ---
    {
        const unsigned short* qp = (const unsigned short*)q + (size_t)i * HIDDEN + 4 * lane;
        ushort4 q4 = *(const ushort4*)qp;
        qsw[w][4 * lane + 0] = b2f(q4.x);
        qsw[w][4 * lane + 1] = b2f(q4.y);
        qsw[w][4 * lane + 2] = b2f(q4.z);
        qsw[w][4 * lane + 3] = b2f(q4.w);
    }

    // --- build jlist: lane scans mask words 2*lane, 2*lane+1; shfl scan ---
    const unsigned int* mrow = mask + (size_t)i * MASK_WORDS;
    unsigned int w0 = mrow[2 * lane], w1 = mrow[2 * lane + 1];
    int c = __popc(w0) + __popc(w1);
    int inc = c;
#pragma unroll
    for (int off = 1; off < 64; off <<= 1) {
        int tt = __shfl_up(inc, off, 64);
        if (lane >= off) inc += tt;
    }
    const int nn0 = __shfl(inc, 63, 64);
    const int nn = (nn0 < CAP) ? nn0 : CAP;
    int pos = inc - c;
    if (pos + c <= CAP) {            // whole-lane guard (cheaper than per-bit)
        int jb = lane * 64;
        while (w0) {
            int b = __ffs(w0) - 1; w0 &= w0 - 1;
            jl[w][pos++] = jb + b;
        }
        jb += 32;
        while (w1) {
            int b = __ffs(w1) - 1; w1 &= w1 - 1;
            jl[w][pos++] = jb + b;
        }
    }
    // (wave-private LDS: compiler's lgkmcnt ordering suffices, no barrier)

    const float* trow = temporal + (size_t)i * N_NODES * 2;
    const unsigned short* kp = (const unsigned short*)k;
    const unsigned short* vp = (const unsigned short*)v;
    const int hsel = lane >> 4;

    float l0 = 0.f, l1 = 0.f, l2 = 0.f, l3 = 0.f;
    float a0 = 0.f, a1 = 0.f, a2 = 0.f, a3 = 0.f;

    for (int c0 = 0; c0 < nn; c0 += 64) {
        const int cend = min(64, nn - c0);
        // ---- Phase A: lane scores neighbor jl[w][c0+lane] for all 4 heads --
        int j = (lane < cend) ? jl[w][c0 + lane] : -1;
        float tb = 0.f;
        if (j >= 0) {
            float dt = trow[(size_t)j * 2];
            tb += 0.2f * (float)((dt >= 0.f)  & (dt <= 5.f));
            tb += 0.1f * (float)((dt >= 5.f)  & (dt <= 15.f));
            tb -= 0.1f * (float)((dt >= 60.f) & (dt <= 240.f));
        }
#pragma unroll
        for (int h = 0; h < 4; ++h) {
            float dot = 0.f;
            if (j >= 0) {
                const unsigned short* krow = kp + (size_t)j * HIDDEN + h * DHEAD;
#pragma unroll
                for (int t = 0; t < 8; ++t) {
                    bf16x8 k8 = *(const bf16x8*)(krow + t * 8);
                    f32x4 qa = *(const f32x4*)(&qsw[w][h * DHEAD + t * 8]);
                    f32x4 qb = *(const f32x4*)(&qsw[w][h * DHEAD + t * 8 + 4]);
                    dot += b2f((unsigned short)k8[0]) * qa[0];
                    dot += b2f((unsigned short)k8[1]) * qa[1];
                    dot += b2f((unsigned short)k8[2]) * qa[2];
                    dot += b2f((unsigned short)k8[3]) * qa[3];
                    dot += b2f((unsigned short)k8[4]) * qb[0];
                    dot += b2f((unsigned short)k8[5]) * qb[1];
                    dot += b2f((unsigned short)k8[6]) * qb[2];
                    dot += b2f((unsigned short)k8[7]) * qb[3];
                }
            }
            float s = (j >= 0) ? dot * 0.125f + tb : -3.0e38f;
            float p = __expf(s);                // invalid lanes -> 0
            float cs = p;
#pragma unroll
            for (int off = 32; off >= 1; off >>= 1)
                cs += __shfl_xor(cs, off, 64);
            pch[w][h][lane] = p;
            if (h == 0) l0 += cs; else if (h == 1) l1 += cs;
            else if (h == 2) l2 += cs; else l3 += cs;
        }
        // ---- Phase B: lane accumulates dims [4*lane, 4*lane+4) ----
        const float* ph = pch[w][hsel];
        int jj = 0;
        for (; jj + 4 <= cend; jj += 4) {
            int ja = jl[w][c0 + jj],     jb2 = jl[w][c0 + jj + 1];
            int jc = jl[w][c0 + jj + 2], jd  = jl[w][c0 + jj + 3];
            float pa = ph[jj], pb = ph[jj + 1], pc = ph[jj + 2], pd = ph[jj + 3];
            ushort4 va = *(const ushort4*)(vp + (size_t)ja  * HIDDEN + 4 * lane);
            ushort4 vb = *(const ushort4*)(vp + (size_t)jb2 * HIDDEN + 4 * lane);
            ushort4 vc = *(const ushort4*)(vp + (size_t)jc  * HIDDEN + 4 * lane);
            ushort4 vd = *(const ushort4*)(vp + (size_t)jd  * HIDDEN + 4 * lane);
            a0 += pa * b2f(va.x) + pb * b2f(vb.x) + pc * b2f(vc.x) + pd * b2f(vd.x);
            a1 += pa * b2f(va.y) + pb * b2f(vb.y) + pc * b2f(vc.y) + pd * b2f(vd.y);
            a2 += pa * b2f(va.z) + pb * b2f(vb.z) + pc * b2f(vc.z) + pd * b2f(vd.z);
            a3 += pa * b2f(va.w) + pb * b2f(vb.w) + pc * b2f(vc.w) + pd * b2f(vd.w);
        }
        for (; jj < cend; ++jj) {
            int jx = jl[w][c0 + jj];
            float px = ph[jj];
            ushort4 vx = *(const ushort4*)(vp + (size_t)jx * HIDDEN + 4 * lane);
            a0 += px * b2f(vx.x);
            a1 += px * b2f(vx.y);
            a2 += px * b2f(vx.z);
            a3 += px * b2f(vx.w);
        }
    }

    float lsel = (hsel == 0) ? l0 : (hsel == 1) ? l1 : (hsel == 2) ? l2 : l3;
    float inv = 1.f / lsel;
    ushort4 o;
    o.x = f2bu(a0 * inv);
    o.y = f2bu(a1 * inv);
    o.z = f2bu(a2 * inv);
    o.w = f2bu(a3 * inv);
    *(ushort4*)((unsigned short*)att + (size_t)i * HIDDEN + 4 * lane) = o;
}

// Dispatch 4: out = att @ Wo + bo, fp32 output
__global__ __launch_bounds__(256) void gemm_out_kernel(
    const bf16* __restrict__ att, const bf16* __restrict__ WoT,
    const float* __restrict__ bo, float* __restrict__ out)
{
    int wave = threadIdx.x >> 6;
    gemm_body<false>(att, WoT, bo, out, HIDDEN,
                     blockIdx.y * 128 + wave * 32, blockIdx.x * 16);
}

// ---------------------------------------------------------------------------
extern "C" void kernel_launch(void* const* d_in, const int* in_sizes, int n_in,
                              void* d_out, int out_size, void* d_ws, size_t ws_size,
                              hipStream_t stream) {
    const float* nf       = (const float*)d_in[0];
    const float* temporal = (const float*)d_in[1];
    const int*   eidx     = (const int*)  d_in[2];
    const float* W_in     = (const float*)d_in[3];
    const float* b_in     = (const float*)d_in[4];
    const float* Wq       = (const float*)d_in[5];
    const float* bq       = (const float*)d_in[6];
    const float* Wk       = (const float*)d_in[7];
    const float* bk       = (const float*)d_in[8];
    const float* Wv       = (const float*)d_in[9];
    const float* bv       = (const float*)d_in[10];
    const float* Wo       = (const float*)d_in[11];
    const float* bo       = (const float*)d_in[12];
    float* out = (float*)d_out;

    char* ws = (char*)d_ws;
    const size_t MiB = 1 << 20, KiB = 1 << 10;
    unsigned int* mask = (unsigned int*)(ws);                  // 2 MiB
    bf16*  nfp   = (bf16*)(ws + 2 * MiB);                      // 512 KiB
    bf16*  WqkvT = (bf16*)(ws + 2 * MiB + 512 * KiB);          // 96 KiB
    float* bqkv  = (float*)(ws + 2 * MiB + 640 * KiB);         // 3 KiB
    bf16*  WoT   = (bf16*)(ws + 3 * MiB);                      // 128 KiB
    bf16*  qb    = (bf16*)(ws + 4 * MiB);                      // 2 MiB
    bf16*  kb    = (bf16*)(ws + 6 * MiB);                      // 2 MiB
    bf16*  vb    = (bf16*)(ws + 8 * MiB);                      // 2 MiB
    bf16*  att   = (bf16*)(ws + 10 * MiB);                     // 2 MiB -> 12 MiB

    // 1. prep: mask zero + nf cvt + combined W'/b' + WoT
    {
        int total = 131072 + N_NODES * KIN + 3 * 256 * KIN + 3 * 256 + 65536;
        prep_kernel<<<(total + 255) / 256, 256, 0, stream>>>(
            nf, W_in, b_in, Wq, bq, Wk, bk, Wv, bv, Wo,
            mask, nfp, WqkvT, bqkv, WoT);
    }

    // 2. q,k,v = nf @ W' + b' (MFMA, K=64, all bf16) + edge/diag scatter
    qkv_scatter_kernel<<<1536 + 528, 256, 0, stream>>>(
        nfp, WqkvT, bqkv, eidx, qb, kb, vb, mask);

    // 3. sparse masked attention (wave = row, barrier-free)
    attn_kernel<<<N_NODES / 4, 256, 0, stream>>>(qb, kb, vb, temporal, mask, att);

    // 4. out = att @ Wo + bo (MFMA)
    gemm_out_kernel<<<dim3(16, 32), 256, 0, stream>>>(att, WoT, bo, out);
}